// Round 1
// 161.970 us; speedup vs baseline: 1.0216x; 1.0216x over previous
//
#include <hip/hip_runtime.h>
#include <math.h>

// ---------------------------------------------------------------------------
// ISTFTHead on gfx950 — fp16 MFMA path, round 12.
//
// Round-11 post-mortem: HW trig in gemm1's epilogue moved the total only
// 167.2 -> 165.5 us => the epilogue cost was never transcendentals; it is the
// 64 scattered scalar f16 global stores/thread (store_a2: ~12 VALU swizzle ops
// each, lanes fanned over ~512B => uncoalesced). Round 12:
//  * gemm1 epilogue: LDS transpose. Reuse Ash(16KB)+Bsh(16KB) as Sr[128][64] /
//    Si[128][64] f16 tiles, XOR-swizzled 16B chunks (col ^ ((row&7)*8)).
//    Scalar ds_write_b16 in acc layout -> ds_read_b128 in A2 fragment layout
//    -> 16B/lane coalesced global_store_dwordx4 (1KB/wave-instr).
//    64 scalar global stores + ~800 VALU  ==>  64 ds_write + 8 ds_read_b128
//    + 8 vector stores. bx*2+kt2l<17 guard == old c<544 clip; zeros for
//    c in [513,544) still written (valid=c<513 zero-fills the tile).
//  * prep_k, gemm2_k, ola_kernel byte-identical to round 11.
//
// Fragment order for mfma_f32_16x16x32_f16 (verified rounds 2-10):
//   A tile: elem(lane,j) = A[m = lane&15][k = (lane>>4)*8 + j]
//   B tile: elem(lane,j) = B[k = (lane>>4)*8 + j][n = lane&15]
//   C/D:    row = (lane>>4)*4 + r, col = lane&15
//   lane fragment = 16 B at tile_base + lane*16.
//
// Workspace map (bytes):
//   A2  [0,          35651584)   16384 x 1088 f16, [mb128][kt34][mts8][l][j]
//                                k<544 = Sr, k>=544 = Si
//   B2  [35651584,   36904960)   mirror basis, [nblk6][kt34][nt6][l][j]
//   A1  [37879808,   54657024)   xh,  [mblk128][kt16][mts8][l][j]
//   B1  [54657024,   55836672)   Wh,  [bx9][kt16][t8][l][j]
//   frames [37879808, 71434240)  16384 x 1024 f16 (overlays A1+B1 — dead by gemm2)
// ---------------------------------------------------------------------------

using half8 = __attribute__((ext_vector_type(8))) _Float16;
using f32x4 = __attribute__((ext_vector_type(4))) float;

#define TWO_PI_OVER_1024 0.006135923151542565f

#define OFF_A2 0
#define OFF_B2 35651584UL
#define OFF_A1 37879808UL
#define OFF_B1 54657024UL
#define OFF_FR 37879808UL

__device__ __forceinline__ float hannf(int s) {
    return 0.5f * (1.0f - __cosf(TWO_PI_OVER_1024 * (float)s));
}

// async global->LDS, 16B per lane. Global addr per-lane; LDS dest wave-uniform.
__device__ __forceinline__ void stage16(const void* g, void* lds) {
    __builtin_amdgcn_global_load_lds(
        (const __attribute__((address_space(1))) void*)g,
        (__attribute__((address_space(3))) void*)lds,
        16, 0, 0);
}

// ---------------- merged prep kernel ----------------
// blocks [0,4096)     : x -> A1 (xh fragments)
// blocks [4096,4384)  : W -> B1 (Wh fragments)
// blocks [4384,4690)  : windowed mirror irfft basis -> B2
__global__ __launch_bounds__(256)
void prep_k(const float* __restrict__ x, const float* __restrict__ W,
            _Float16* __restrict__ A1, _Float16* __restrict__ B1,
            _Float16* __restrict__ B2)
{
    const int bid = blockIdx.x;
    if (bid < 4096) {
        // x (16384x512 f32) -> A1, [mblk128][kt16][mts8][l][j]
        const size_t tid = (size_t)bid * 256 + threadIdx.x;      // 1,048,576
        const int l   = (int)(tid & 63);
        const size_t f = tid >> 6;
        const int mts = (int)(f & 7);
        const size_t g = f >> 3;
        const int kt  = (int)(g & 15);
        const int mtb = (int)(g >> 4);
        const int m   = mtb * 128 + mts * 16 + (l & 15);
        const int k0  = kt * 32 + (l >> 4) * 8;
        const float* xp = x + (size_t)m * 512 + k0;
        const float4 v0 = *(const float4*)xp;
        const float4 v1 = *(const float4*)(xp + 4);
        const float vv[8] = {v0.x, v0.y, v0.z, v0.w, v1.x, v1.y, v1.z, v1.w};
        half8 o;
#pragma unroll
        for (int j = 0; j < 8; ++j) o[j] = (_Float16)vv[j];
        *(half8*)(A1 + tid * 8) = o;
    } else if (bid < 4384) {
        // W (512x1026 f32) -> B1, per bx(0..8): tiles 0..3 mag, 4..7 phase.
        const int tid = (bid - 4096) * 256 + threadIdx.x;        // 73,728
        const int l  = tid & 63;
        const int f  = tid >> 6;
        const int t8 = f & 7;
        const int g  = f >> 3;
        const int kt = g & 15;
        const int bx = g >> 4;
        const int side = t8 >> 2;
        const int nt   = t8 & 3;
        const int c    = bx * 64 + nt * 16 + (l & 15);           // [0,576)
        const int k0   = kt * 32 + (l >> 4) * 8;
        const int wcol = side ? (513 + c) : c;
        half8 o;
#pragma unroll
        for (int j = 0; j < 8; ++j) {
            float v = (c < 513) ? W[(size_t)(k0 + j) * 1026 + wcol] : 0.0f;
            o[j] = (_Float16)v;
        }
        *(half8*)(B1 + (size_t)tid * 8) = o;
    } else {
        // basis -> B2, [nblk6][kt34][nt6][l][j]; kk<544 cos, kk>=544 -sin.
        const int tid = (bid - 4384) * 256 + threadIdx.x;        // 78,336
        const int l  = tid & 63;
        const int f  = tid >> 6;
        const int nt = f % 6;
        const int g  = f / 6;
        const int kt = g % 34;
        const int nblk = g / 34;
        const int n  = nblk * 96 + nt * 16 + (l & 15);
        const int kk0 = kt * 32 + (l >> 4) * 8;
        const float win = hannf(n) * (1.0f / 1024.0f);
        half8 o;
#pragma unroll
        for (int j = 0; j < 8; ++j) {
            const int kk = kk0 + j;
            float v = 0.0f;
            if (kk < 544) {
                const int k = kk;
                if (k < 513) {
                    const float coef = (k == 0 || k == 512) ? 1.0f : 2.0f;
                    v = coef * __cosf(TWO_PI_OVER_1024 * (float)((k * n) & 1023)) * win;
                }
            } else {
                const int k = kk - 544;
                if (k < 513) {
                    const float coef = (k == 0 || k == 512) ? 1.0f : 2.0f;
                    v = -coef * __sinf(TWO_PI_OVER_1024 * (float)((k * n) & 1023)) * win;
                }
            }
            o[j] = (_Float16)v;
        }
        *(half8*)(B2 + (size_t)tid * 8) = o;
    }
}

// ---------------- GEMM1: h = xh@Wh + b, fused activation -------------------
// Block 128m x 8 n-tiles (4 mag + 4 phase). Wave grid 2x2: wave w owns
// m-tiles wm..wm+3, n-tiles {2q,2q+1, 4+2q,5+2q} (matching mag+phase cols).
// 8 steps x 2 kt; per step per wave: 8 stage16, 16 ds_read_b128, 32 MFMA.
// Epilogue: Sr/Si transposed through reused LDS, coalesced 16B fragment stores.

__global__ __launch_bounds__(256, 4)
void gemm1_k(const _Float16* __restrict__ A, const _Float16* __restrict__ B,
             const float* __restrict__ bias, _Float16* __restrict__ A2)
{
    __shared__ _Float16 Ash[2][8 * 512];   // 2 kt x 8 m-tiles (16 KB)
    __shared__ _Float16 Bsh[2][8 * 512];   // 2 kt x 8 n-tiles (16 KB)
    const int t = threadIdx.x, w = t >> 6, l = t & 63;

    // XCD-aware swizzle: 1152 blocks, 144 per XCD = 16 mblk x 9 bx.
    const int lin = blockIdx.x;
    const int xcd = lin & 7, slot = lin >> 3;
    const int mblk = xcd * 16 + slot / 9;
    const int bx   = slot % 9;

    const int wm = (w & 1) * 4;            // m-tile base
    const int q  = w >> 1;                 // n-pair index
    const int jt[4] = {2 * q, 2 * q + 1, 4 + 2 * q, 5 + 2 * q};

    f32x4 acc[4][4];                       // [m-tile][0..1 mag | 2..3 phase]
#pragma unroll
    for (int i = 0; i < 4; ++i)
#pragma unroll
        for (int j = 0; j < 4; ++j) acc[i][j] = (f32x4)0.0f;

    const int lane8 = l * 8;
    const _Float16* Ab = A + ((size_t)mblk * 16 * 8) * 512 + lane8;
    const _Float16* Bb = B + ((size_t)bx * 16 * 8) * 512 + lane8;

    for (int step = 0; step < 8; ++step) {
        const int kt0 = 2 * step;
        __syncthreads();
#pragma unroll
        for (int i = 0; i < 4; ++i) {
            const int s = 4 * w + i;
            const int u = s >> 3, r = s & 7;
            stage16(Ab + ((size_t)(kt0 + u) * 8 + r) * 512, &Ash[u][r * 512]);
            stage16(Bb + ((size_t)(kt0 + u) * 8 + r) * 512, &Bsh[u][r * 512]);
        }
        __syncthreads();

#pragma unroll
        for (int u = 0; u < 2; ++u) {
            half8 a[4], b[4];
#pragma unroll
            for (int i = 0; i < 4; ++i)
                a[i] = *(const half8*)&Ash[u][(wm + i) * 512 + lane8];
#pragma unroll
            for (int j = 0; j < 4; ++j)
                b[j] = *(const half8*)&Bsh[u][jt[j] * 512 + lane8];
#pragma unroll
            for (int i = 0; i < 4; ++i)
#pragma unroll
                for (int j = 0; j < 4; ++j)
                    acc[i][j] = __builtin_amdgcn_mfma_f32_16x16x32_f16(a[i], b[j], acc[i][j], 0, 0, 0);
        }
    }

    // ---- epilogue: activation -> LDS transpose -> coalesced fragment stores.
    // Sr tile (128 rows x 64 local cols) reuses Ash; Si tile reuses Bsh.
    // XOR-swizzle 16B chunks: idx = row*64 + (col ^ ((row&7)*8)).
    _Float16* SrT = &Ash[0][0];            // 8192 f16 = 16 KB
    _Float16* SiT = &Bsh[0][0];            // 8192 f16 = 16 KB

    __syncthreads();                       // all waves done reading Ash/Bsh
    const int r4 = (l >> 4) * 4, c16 = l & 15;
#pragma unroll
    for (int i = 0; i < 4; ++i) {
        const int row0 = (wm + i) * 16 + r4;          // local row base [0,128)
#pragma unroll
        for (int p = 0; p < 2; ++p) {
            const int cl = (2 * q + p) * 16 + c16;    // local col [0,64)
            const int c  = bx * 64 + cl;              // global S col [0,576)
            const bool valid = (c < 513);
            const float bm = valid ? bias[c] : 0.0f;
            const float bp = valid ? bias[513 + c] : 0.0f;
#pragma unroll
            for (int r = 0; r < 4; ++r) {
                float Sr = 0.0f, Si = 0.0f;
                if (valid) {
                    const float mag = fminf(__expf(acc[i][p][r] + bm), 100.0f);
                    const float ph  = acc[i][2 + p][r] + bp;
                    Sr = mag * __cosf(ph);
                    Si = mag * __sinf(ph);
                }
                const int row = row0 + r;
                const int idx = row * 64 + (cl ^ ((row & 7) * 8));
                SrT[idx] = (_Float16)Sr;
                SiT[idx] = (_Float16)Si;
            }
        }
    }
    __syncthreads();

    // 16 fragment tiles per side (kt2l in {0,1} x mts in [0,8)); 4 per wave.
    // Lane l holds 16B at A2 tile_base + l*16 -> 1KB coalesced per wave-store.
#pragma unroll
    for (int f = 0; f < 4; ++f) {
        const int tau  = w * 4 + f;
        const int kt2l = tau >> 3, mts = tau & 7;
        if (bx * 2 + kt2l < 17) {          // == old c<544 clip (skips bx=8 hi-kt)
            const int row = mts * 16 + (l & 15);
            const int kl  = kt2l * 32 + (l >> 4) * 8;          // [0,64)
            const int idx = row * 64 + (kl ^ ((row & 7) * 8));
            const half8 vr = *(const half8*)&SrT[idx];
            const half8 vi = *(const half8*)&SiT[idx];
            const int ktr = bx * 2 + kt2l;                     // Sr k-tile
            const int kti = 17 + ktr;                          // Si k-tile
            *(half8*)(A2 + ((((size_t)mblk * 34 + ktr) * 8 + mts) * 64 + l) * 8) = vr;
            *(half8*)(A2 + ((((size_t)mblk * 34 + kti) * 8 + mts) * 64 + l) * 8) = vi;
        }
    }
}

// ---------------- GEMM2: mirror-symmetric frames = A2 @ basis ---------------
// Byte-identical to round 11 (= round 6 structure, best measured).

__device__ __forceinline__ void mma43(const _Float16* __restrict__ As,
                                      const _Float16* __restrict__ Bs,
                                      int wm, int wn, int lane16, f32x4 (&acc)[4][3])
{
    half8 a[4], b[3];
#pragma unroll
    for (int i = 0; i < 4; ++i) a[i] = *(const half8*)&As[(wm + i) * 512 + lane16];
#pragma unroll
    for (int j = 0; j < 3; ++j) b[j] = *(const half8*)&Bs[(wn + j) * 512 + lane16];
#pragma unroll
    for (int i = 0; i < 4; ++i)
#pragma unroll
        for (int j = 0; j < 3; ++j)
            acc[i][j] = __builtin_amdgcn_mfma_f32_16x16x32_f16(a[i], b[j], acc[i][j], 0, 0, 0);
}

__global__ __launch_bounds__(256, 3)
void gemm2_k(const _Float16* __restrict__ A, const _Float16* __restrict__ Bas,
             _Float16* __restrict__ C)
{
    __shared__ _Float16 As[2][8 * 512];   // 2 k-tiles x 128 m-rows
    __shared__ _Float16 Bs[2][6 * 512];   // 2 k-tiles x 96 n-cols
    const int t = threadIdx.x, w = t >> 6, l = t & 63;

    // XCD-aware swizzle: 768 blocks, 96 per XCD = 16 mblk x 6 nblk.
    const int lin = blockIdx.x;
    const int xcd = lin & 7, slot = lin >> 3;
    const int mblk = xcd * 16 + slot / 6;   // [0,128)
    const int nblk = slot % 6;              // [0,6)

    const int wm = (w & 1) * 4, wn = (w >> 1) * 3;

    f32x4 accC[4][3], accD[4][3];
#pragma unroll
    for (int i = 0; i < 4; ++i)
#pragma unroll
        for (int j = 0; j < 3; ++j) { accC[i][j] = (f32x4)0.0f; accD[i][j] = (f32x4)0.0f; }

    const int lane16 = l * 8;

    for (int step = 0; step < 17; ++step) {
        const int kt0 = 2 * step;
        __syncthreads();
#pragma unroll
        for (int i = 0; i < 4; ++i) {
            const int ta = 4 * w + i;
            const int u = ta >> 3, mts = ta & 7;
            const _Float16* Ag = A + ((((size_t)mblk * 34 + (kt0 + u)) * 8 + mts) * 512) + lane16;
            stage16(Ag, &As[u][mts * 512]);
        }
#pragma unroll
        for (int i = 0; i < 3; ++i) {
            const int tb = 3 * w + i;
            const int u = tb / 6, nt = tb % 6;
            const _Float16* Bg = Bas + ((((size_t)nblk * 34 + (kt0 + u)) * 6 + nt) * 512) + lane16;
            stage16(Bg, &Bs[u][nt * 512]);
        }
        __syncthreads();

#pragma unroll
        for (int u = 0; u < 2; ++u) {
            const int kt = kt0 + u;
            if (kt < 17) mma43(As[u], Bs[u], wm, wn, lane16, accC);
            else         mma43(As[u], Bs[u], wm, wn, lane16, accD);
        }
    }

    // epilogue: frames[n] = C+D, frames[1024-n] = C-D  (hann(1024-n)=hann(n))
    const int r4 = (l >> 4) * 4, c0 = l & 15;
#pragma unroll
    for (int i = 0; i < 4; ++i) {
        const int m = mblk * 128 + (wm + i) * 16 + r4;
#pragma unroll
        for (int j = 0; j < 3; ++j) {
            const int n = nblk * 96 + (wn + j) * 16 + c0;
#pragma unroll
            for (int r = 0; r < 4; ++r) {
                const float cv = accC[i][j][r];
                const float dv = accD[i][j][r];
                _Float16* row = C + (size_t)(m + r) * 1024;
                if (n < 513)           row[n]        = (_Float16)(cv + dv);
                if (n >= 1 && n < 512) row[1024 - n] = (_Float16)(cv - dv);
            }
        }
    }
}

// ---------------- overlap-add + envelope ------------------------------------

__global__ __launch_bounds__(256)
void ola_kernel(const _Float16* __restrict__ frames, float* __restrict__ out)
{
    const int idx = blockIdx.x * 256 + threadIdx.x;   // over 8 * 524288
    const int b = idx >> 19;
    const int j = idx & 524287;
    const int n = j + 384;

    int t_hi = n >> 8;
    if (t_hi > 2047) t_hi = 2047;
    const int t_lo = (n >= 1023) ? ((n - 1023 + 255) >> 8) : 0;

    float acc = 0.0f, env = 0.0f;
    for (int tt = t_lo; tt <= t_hi; ++tt) {
        const int s = n - (tt << 8);
        const float wv = hannf(s);
        acc += (float)frames[(((size_t)(b * 2048 + tt)) << 10) + s];
        env += wv * wv;
    }
    out[idx] = acc / env;
}

// ---------------- launch ----------------------------------------------------

extern "C" void kernel_launch(void* const* d_in, const int* in_sizes, int n_in,
                              void* d_out, int out_size, void* d_ws, size_t ws_size,
                              hipStream_t stream)
{
    const float* x = (const float*)d_in[0];   // 16384 x 512
    const float* W = (const float*)d_in[1];   // 512 x 1026
    const float* b = (const float*)d_in[2];   // 1026
    float* out = (float*)d_out;               // 8 x 524288
    char* ws = (char*)d_ws;

    _Float16* A2 = (_Float16*)(ws + OFF_A2);
    _Float16* B2 = (_Float16*)(ws + OFF_B2);
    _Float16* A1 = (_Float16*)(ws + OFF_A1);
    _Float16* B1 = (_Float16*)(ws + OFF_B1);
    _Float16* frames = (_Float16*)(ws + OFF_FR);

    prep_k<<<4690, 256, 0, stream>>>(x, W, A1, B1, B2);

    gemm1_k<<<1152, 256, 0, stream>>>(A1, B1, b, A2);
    gemm2_k<<<768, 256, 0, stream>>>(A2, B2, frames);

    ola_kernel<<<out_size / 256, 256, 0, stream>>>(frames, out);
}